// Round 4
// baseline (254.010 us; speedup 1.0000x reference)
//
#include <hip/hip_runtime.h>
#include <hip/hip_bf16.h>
#include <cstdint>
#include <cstddef>

// Problem constants
#define NB   64
#define NS   8
#define DIM  2048
#define FF   4096
#define NE   8
#define TOK  512            // NB*NS
#define NPAIR 1024          // TOK*2

// GEMM tiling
#define BM   192            // M capacity per pass (Binomial(512,1/4): mean 128, +6.5 sigma)
#define BN   64             // N-cols per block
#define BK   32             // K per stage (one 16x16x32 MFMA K-slice)

typedef __attribute__((ext_vector_type(4))) float f32x4;
typedef __attribute__((ext_vector_type(8))) short bf16x8;

#define MFMA16(a, b, c) __builtin_amdgcn_mfma_f32_16x16x32_bf16((a), (b), (c), 0, 0, 0)

// counted vmcnt waits + raw barrier ("memory" clobber pins LDS reads below)
#define VMCNT0 asm volatile("s_waitcnt vmcnt(0)" ::: "memory")
#define VMCNT1 asm volatile("s_waitcnt vmcnt(1)" ::: "memory")
#define VMCNT2 asm volatile("s_waitcnt vmcnt(2)" ::: "memory")
#define WGBAR  do { asm volatile("s_barrier" ::: "memory"); \
                    __builtin_amdgcn_sched_barrier(0); } while (0)

// round-half-up fp32 -> bf16 (0.5 ulp, 2 VALU ops)
static __device__ __forceinline__ short f2bf(float f) {
    unsigned u = __builtin_bit_cast(unsigned, f);
    return (short)((u + 0x8000u) >> 16);
}

// async global->LDS DMA, 16 bytes/lane; LDS dest must be wave-linear (base+lane*16),
// global source may be per-lane arbitrary (swizzle the SOURCE, never the dest).
static __device__ __forceinline__ void async16(void* l, const void* g) {
    __builtin_amdgcn_global_load_lds(
        (const __attribute__((address_space(1))) void*)g,
        (__attribute__((address_space(3))) void*)l, 16, 0, 0);
}

static __device__ __forceinline__ int inc3(int i) { return (i == 2) ? 0 : i + 1; }

// ---------------------------------------------------------------------------
// Kernel 1: gating (logits -> top-2 -> softmax) + x -> bf16 preconvert.
// ---------------------------------------------------------------------------
__global__ void gate_topk(const float* __restrict__ x, const float* __restrict__ gw,
                          unsigned short* __restrict__ xbf,
                          int* __restrict__ tok_expert, float* __restrict__ tok_gatew) {
    int token = blockIdx.x;
    int lane  = threadIdx.x;
    const float* xr = x + (size_t)token * DIM;

    float acc[NE];
#pragma unroll
    for (int e = 0; e < NE; ++e) acc[e] = 0.f;

    for (int d0 = lane * 8; d0 < DIM; d0 += 64 * 8) {
        float4 xa = *(const float4*)(xr + d0);
        float4 xb = *(const float4*)(xr + d0 + 4);
        bf16x8 v;
        v[0] = f2bf(xa.x); v[1] = f2bf(xa.y); v[2] = f2bf(xa.z); v[3] = f2bf(xa.w);
        v[4] = f2bf(xb.x); v[5] = f2bf(xb.y); v[6] = f2bf(xb.z); v[7] = f2bf(xb.w);
        *(bf16x8*)(xbf + (size_t)token * DIM + d0) = v;
#pragma unroll
        for (int j = 0; j < 8; ++j) {
            float xv = (j < 4) ? ((const float*)&xa)[j] : ((const float*)&xb)[j - 4];
            const float4* g = (const float4*)(gw + (size_t)(d0 + j) * NE);
            float4 g0 = g[0], g1 = g[1];
            acc[0] += xv * g0.x; acc[1] += xv * g0.y;
            acc[2] += xv * g0.z; acc[3] += xv * g0.w;
            acc[4] += xv * g1.x; acc[5] += xv * g1.y;
            acc[6] += xv * g1.z; acc[7] += xv * g1.w;
        }
    }
#pragma unroll
    for (int off = 32; off >= 1; off >>= 1) {
#pragma unroll
        for (int e = 0; e < NE; ++e) acc[e] += __shfl_down(acc[e], off);
    }
    if (lane == 0) {
        float b1 = -1e30f, b2 = -1e30f; int i1 = 0, i2 = 0;
#pragma unroll
        for (int e = 0; e < NE; ++e) {
            float v = acc[e];
            if (v > b1) { b2 = b1; i2 = i1; b1 = v; i1 = e; }
            else if (v > b2) { b2 = v; i2 = e; }
        }
        float t = __expf(b2 - b1);
        tok_expert[token * 2 + 0] = i1;
        tok_expert[token * 2 + 1] = i2;
        tok_gatew[token * 2 + 0] = 1.f / (1.f + t);
        tok_gatew[token * 2 + 1] = t / (1.f + t);
    }
}

// ---------------------------------------------------------------------------
// Kernel 2: deterministic per-expert token lists (wave-per-expert ballot scan)
// ---------------------------------------------------------------------------
__global__ void build_lists(const int* __restrict__ tok_expert,
                            const float* __restrict__ tok_gatew,
                            int* __restrict__ counts, int* __restrict__ offsets,
                            int* __restrict__ row_token, float* __restrict__ row_gatew,
                            int* __restrict__ pair_row) {
    __shared__ int s_off[NE];
    __shared__ int s_cnt[NE];
    int e    = threadIdx.x >> 6;
    int lane = threadIdx.x & 63;
    unsigned long long lt = (1ull << lane) - 1ull;

    int cnt = 0;
    for (int base = 0; base < NPAIR; base += 64) {
        int id = tok_expert[base + lane];
        unsigned long long m = __ballot(id == e);
        cnt += __popcll(m);
    }
    if (lane == 0) s_cnt[e] = cnt;
    __syncthreads();
    if (threadIdx.x == 0) {
        int o = 0;
        for (int i = 0; i < NE; ++i) {
            int c = s_cnt[i];
            counts[i] = c; offsets[i] = o; s_off[i] = o; o += c;
        }
    }
    __syncthreads();

    int rbase = s_off[e];
    for (int base = 0; base < NPAIR; base += 64) {
        int entry = base + lane;
        int id = tok_expert[entry];
        bool match = (id == e);
        unsigned long long m = __ballot(match);
        int pre = __popcll(m & lt);
        if (match) {
            int row = rbase + pre;
            row_token[row] = entry >> 1;
            row_gatew[row] = tok_gatew[entry];
            pair_row[entry] = row;
        }
        rbase += __popcll(m);
    }
}

// ---------------------------------------------------------------------------
// Kernel 3: H = silu(Xbf*w1) .* (Xbf*w3) per expert group.
// grid = 512 (8 experts x 64 f-tiles of BN=64). 512 thr = 8 waves (4M x 2N).
// Counted-vmcnt pipeline: A double-buffered (staged 1 ahead, L2-resident),
// B1/B3 triple-buffered (staged 2 ahead, HBM stream). One raw barrier/iter.
// ---------------------------------------------------------------------------
__global__ __launch_bounds__(512, 4) void ffn1(
    const unsigned short* __restrict__ xbf, const float* __restrict__ w1,
    const float* __restrict__ w3,
    const int* __restrict__ counts, const int* __restrict__ offsets,
    const int* __restrict__ row_token, unsigned short* __restrict__ Hbuf) {
    __shared__ __align__(16) unsigned short Ab[2][BM * BK];   // 24 KB
    __shared__ __align__(16) float B1[3][BK][BN];             // 24 KB
    __shared__ __align__(16) float B3[3][BK][BN];             // 24 KB

    int bid = blockIdx.x;
    int e  = bid >> 6;
    int f0 = (bid & 63) * BN;

    int Me = counts[e];
    if (Me == 0) return;
    int off = offsets[e];

    int t = threadIdx.x;
    int lane = t & 63;
    int w = t >> 6;
    int wm = w >> 1, wn = w & 1;                 // 4 M-waves x 2 N-waves
    int l15 = lane & 15, lg = lane >> 4;

    const float* w1e = w1 + (size_t)e * DIM * FF + f0;
    const float* w3e = w3 + (size_t)e * DIM * FF + f0;

    // B staging: thread t -> chunk (k = t>>4, cc = t&15); source col-chunk XOR'd
    int bk = t >> 4, bcc = t & 15;
    int bcol = (bcc ^ (((bk >> 3) & 1) << 2)) * 4;
    const float* b1src = w1e + (size_t)bk * FF + bcol;
    const float* b3src = w3e + (size_t)bk * FF + bcol;

    const int NSTG = DIM / BK;                   // 64

    for (int sup = 0; sup * BM < Me; ++sup) {
        int mbase = sup * BM;
        // A staging sources: chunk i = it*512+t -> (m = i>>2, c = i&3);
        // LDS slot c holds source chunk c^(m&3)
        const unsigned short* asrc0;
        const unsigned short* asrc1;
        {
            int m0 = t >> 2, c0 = t & 3;
            int rl0 = mbase + m0;
            int tok0 = row_token[off + ((rl0 < Me) ? rl0 : (Me - 1))];
            asrc0 = xbf + (size_t)tok0 * DIM + ((c0 ^ (m0 & 3)) << 3);
            int i1i = 512 + t;
            int m1 = i1i >> 2, c1 = i1i & 3;
            int rl1 = mbase + m1;
            int tok1 = row_token[off + ((rl1 < Me) ? rl1 : (Me - 1))];
            asrc1 = xbf + (size_t)tok1 * DIM + ((c1 ^ (m1 & 3)) << 3);
        }

        f32x4 acc1[3][2], acc3[3][2];
#pragma unroll
        for (int f = 0; f < 3; ++f)
#pragma unroll
            for (int nf = 0; nf < 2; ++nf) {
                acc1[f][nf] = (f32x4){0.f, 0.f, 0.f, 0.f};
                acc3[f][nf] = (f32x4){0.f, 0.f, 0.f, 0.f};
            }

        auto stageA = [&](int buf, int k0) {
            async16(&Ab[buf][(size_t)t * 8], asrc0 + k0);
            if (t < 256) async16(&Ab[buf][(size_t)(512 + t) * 8], asrc1 + k0);
        };
        auto stageB = [&](int buf, int k0) {
            async16((float*)&B1[buf][0][0] + t * 4, b1src + (size_t)k0 * FF);
            async16((float*)&B3[buf][0][0] + t * 4, b3src + (size_t)k0 * FF);
        };

        __syncthreads();               // protect buffers across sup passes
        // prologue: A(0); B(0); B(1)
        stageA(0, 0);
        stageB(0, 0);
        stageB(1, BK);

        int bA = 0, bB = 0, bBs = 2;   // compute-A, compute-B, B stage target
        for (int s = 0; s < NSTG; ++s) {
            // wait: A(s) and B(s) landed; keep B(s+1) in flight (steady state)
            if (s >= NSTG - 2) { VMCNT0; } else { VMCNT2; }
            WGBAR;
            if (s + 1 < NSTG) stageA(bA ^ 1, (s + 1) * BK);
            if (s + 2 < NSTG) stageB(bBs, (s + 2) * BK);

            // A fragments: one ds_read_b128 each
            bf16x8 a[3];
#pragma unroll
            for (int f = 0; f < 3; ++f) {
                int m = wm * 48 + f * 16 + l15;
                a[f] = *(const bf16x8*)&Ab[bA][(size_t)m * BK + ((lg ^ (m & 3)) << 3)];
            }
            // B fragments: 8 conflict-free scalar reads + cvt each
#pragma unroll
            for (int nf = 0; nf < 2; ++nf) {
                int col = wn * 32 + nf * 16 + l15;
                int pp = col ^ ((lg & 1) << 4);
                bf16x8 b1f, b3f;
#pragma unroll
                for (int j = 0; j < 8; ++j) {
                    b1f[j] = f2bf(B1[bB][lg * 8 + j][pp]);
                    b3f[j] = f2bf(B3[bB][lg * 8 + j][pp]);
                }
#pragma unroll
                for (int f = 0; f < 3; ++f) {
                    acc1[f][nf] = MFMA16(a[f], b1f, acc1[f][nf]);
                    acc3[f][nf] = MFMA16(a[f], b3f, acc3[f][nf]);
                }
            }
            bA ^= 1; bB = inc3(bB); bBs = inc3(bBs);
        }

        // epilogue: silu(a1)*a3 -> bf16 H
#pragma unroll
        for (int f = 0; f < 3; ++f)
#pragma unroll
            for (int nf = 0; nf < 2; ++nf)
#pragma unroll
                for (int r = 0; r < 4; ++r) {
                    int rl = mbase + wm * 48 + f * 16 + lg * 4 + r;
                    if (rl < Me) {
                        float a1 = acc1[f][nf][r], a3 = acc3[f][nf][r];
                        float h = (a1 / (1.f + __expf(-a1))) * a3;
                        Hbuf[(size_t)(off + rl) * FF + f0 + wn * 32 + nf * 16 + l15] =
                            (unsigned short)f2bf(h);
                    }
                }
    }
}

// ---------------------------------------------------------------------------
// Kernel 4: OutPair = (H @ w2) * gate_weight.  grid = 256 (8 experts x 32 tiles).
// Same counted-vmcnt pipeline; B single async16/thread -> wait vmcnt(1).
// ---------------------------------------------------------------------------
__global__ __launch_bounds__(512, 4) void ffn2(
    const unsigned short* __restrict__ Hbuf, const float* __restrict__ w2,
    const int* __restrict__ counts, const int* __restrict__ offsets,
    const float* __restrict__ row_gatew, float* __restrict__ OP) {
    __shared__ __align__(16) unsigned short Ab[2][BM * BK];   // 24 KB
    __shared__ __align__(16) float Bw[3][BK][BN];             // 24 KB

    int bid = blockIdx.x;
    int e  = bid >> 5;
    int d0 = (bid & 31) * BN;

    int Me = counts[e];
    if (Me == 0) return;
    int off = offsets[e];

    int t = threadIdx.x;
    int lane = t & 63;
    int w = t >> 6;
    int wm = w >> 1, wn = w & 1;
    int l15 = lane & 15, lg = lane >> 4;

    const float* w2e = w2 + (size_t)e * FF * DIM + d0;

    int bk = t >> 4, bcc = t & 15;
    int bcol = (bcc ^ (((bk >> 3) & 1) << 2)) * 4;
    const float* bsrc = w2e + (size_t)bk * DIM + bcol;

    const int NSTG = FF / BK;                    // 128

    for (int sup = 0; sup * BM < Me; ++sup) {
        int mbase = sup * BM;
        const unsigned short* asrc0;
        const unsigned short* asrc1;
        {
            int m0 = t >> 2, c0 = t & 3;
            int rl0 = mbase + m0;
            asrc0 = Hbuf + (size_t)(off + ((rl0 < Me) ? rl0 : (Me - 1))) * FF
                         + ((c0 ^ (m0 & 3)) << 3);
            int i1i = 512 + t;
            int m1 = i1i >> 2, c1 = i1i & 3;
            int rl1 = mbase + m1;
            asrc1 = Hbuf + (size_t)(off + ((rl1 < Me) ? rl1 : (Me - 1))) * FF
                         + ((c1 ^ (m1 & 3)) << 3);
        }

        f32x4 acc[3][2];
#pragma unroll
        for (int f = 0; f < 3; ++f)
#pragma unroll
            for (int nf = 0; nf < 2; ++nf) acc[f][nf] = (f32x4){0.f, 0.f, 0.f, 0.f};

        auto stageA = [&](int buf, int k0) {
            async16(&Ab[buf][(size_t)t * 8], asrc0 + k0);
            if (t < 256) async16(&Ab[buf][(size_t)(512 + t) * 8], asrc1 + k0);
        };
        auto stageB = [&](int buf, int k0) {
            async16((float*)&Bw[buf][0][0] + t * 4, bsrc + (size_t)k0 * DIM);
        };

        __syncthreads();
        stageA(0, 0);
        stageB(0, 0);
        stageB(1, BK);

        int bA = 0, bB = 0, bBs = 2;
        for (int s = 0; s < NSTG; ++s) {
            if (s >= NSTG - 2) { VMCNT0; } else { VMCNT1; }
            WGBAR;
            if (s + 1 < NSTG) stageA(bA ^ 1, (s + 1) * BK);
            if (s + 2 < NSTG) stageB(bBs, (s + 2) * BK);

            bf16x8 a[3];
#pragma unroll
            for (int f = 0; f < 3; ++f) {
                int m = wm * 48 + f * 16 + l15;
                a[f] = *(const bf16x8*)&Ab[bA][(size_t)m * BK + ((lg ^ (m & 3)) << 3)];
            }
#pragma unroll
            for (int nf = 0; nf < 2; ++nf) {
                int col = wn * 32 + nf * 16 + l15;
                int pp = col ^ ((lg & 1) << 4);
                bf16x8 bf_;
#pragma unroll
                for (int j = 0; j < 8; ++j)
                    bf_[j] = f2bf(Bw[bB][lg * 8 + j][pp]);
#pragma unroll
                for (int f = 0; f < 3; ++f)
                    acc[f][nf] = MFMA16(a[f], bf_, acc[f][nf]);
            }
            bA ^= 1; bB = inc3(bB); bBs = inc3(bBs);
        }

#pragma unroll
        for (int f = 0; f < 3; ++f)
#pragma unroll
            for (int nf = 0; nf < 2; ++nf)
#pragma unroll
                for (int r = 0; r < 4; ++r) {
                    int rl = mbase + wm * 48 + f * 16 + lg * 4 + r;
                    if (rl < Me) {
                        int grow = off + rl;
                        float g = row_gatew[grow];
                        OP[(size_t)grow * DIM + d0 + wn * 32 + nf * 16 + l15] =
                            acc[f][nf][r] * g;
                    }
                }
    }
}

// ---------------------------------------------------------------------------
// Kernel 5: out[token] = OP[pair0] + OP[pair1]
// ---------------------------------------------------------------------------
__global__ void combine(const float* __restrict__ OP, const int* __restrict__ pair_row,
                        float* __restrict__ out) {
    int idx = blockIdx.x * blockDim.x + threadIdx.x;
    int token = idx >> 9;
    int q = idx & 511;
    int r0 = pair_row[token * 2 + 0];
    int r1 = pair_row[token * 2 + 1];
    float4 a = *(const float4*)(OP + (size_t)r0 * DIM + q * 4);
    float4 b = *(const float4*)(OP + (size_t)r1 * DIM + q * 4);
    float4 o;
    o.x = a.x + b.x; o.y = a.y + b.y; o.z = a.z + b.z; o.w = a.w + b.w;
    *(float4*)(out + (size_t)token * DIM + q * 4) = o;
}

// ---------------------------------------------------------------------------
extern "C" void kernel_launch(void* const* d_in, const int* in_sizes, int n_in,
                              void* d_out, int out_size, void* d_ws, size_t ws_size,
                              hipStream_t stream) {
    const float* x  = (const float*)d_in[0];
    const float* gw = (const float*)d_in[1];
    const float* w1 = (const float*)d_in[2];
    const float* w3 = (const float*)d_in[3];
    const float* w2 = (const float*)d_in[4];
    float* out = (float*)d_out;

    char* ws = (char*)d_ws;
    unsigned short* Hbuf = (unsigned short*)ws;                 // 8 MB bf16 [1024][4096]
    float* OP            = (float*)(ws + 8388608);              // 8 MB f32  [1024][2048]
    unsigned short* xbf  = (unsigned short*)(ws + 16777216);    // 2 MB bf16 [512][2048]
    char* meta           = ws + 18874368;
    int*   tok_expert = (int*)(meta);
    float* tok_gatew  = (float*)(meta + 4096);
    int*   counts     = (int*)(meta + 8192);
    int*   offsets    = (int*)(meta + 8224);
    int*   row_token  = (int*)(meta + 8256);
    float* row_gatew  = (float*)(meta + 12352);
    int*   pair_row   = (int*)(meta + 16448);

    gate_topk<<<TOK, 64, 0, stream>>>(x, gw, xbf, tok_expert, tok_gatew);
    build_lists<<<1, 512, 0, stream>>>(tok_expert, tok_gatew, counts, offsets,
                                       row_token, row_gatew, pair_row);
    ffn1<<<NE * 64, 512, 0, stream>>>(xbf, w1, w3, counts, offsets, row_token, Hbuf);
    ffn2<<<NE * 32, 512, 0, stream>>>(Hbuf, w2, counts, offsets, row_gatew, OP);
    combine<<<1024, 256, 0, stream>>>(OP, pair_row, out);
}